// Round 5
// baseline (284.791 us; speedup 1.0000x reference)
//
#include <hip/hip_runtime.h>

#define TT 1024
#define DD 64
#define MAXREL 16
#define NV 33
#define QBLK 8
#define SCALE 0.125f
#define BH 64

typedef short bf16x8 __attribute__((ext_vector_type(8)));
typedef short bf16x4 __attribute__((ext_vector_type(4)));
typedef float f32x4 __attribute__((ext_vector_type(4)));

static __device__ inline short f2bf(float f) {
    union { float f; unsigned u; } x; x.f = f;
    unsigned u = x.u;
    u += 0x7fff + ((u >> 16) & 1);   // RNE
    return (short)(u >> 16);
}
static __device__ inline float bf2f(short s) {
    union { unsigned u; float f; } x;
    x.u = ((unsigned)(unsigned short)s) << 16;
    return x.f;
}
static __device__ inline bf16x8 pack8(float4 a, float4 b) {
    bf16x8 r;
    r[0]=f2bf(a.x); r[1]=f2bf(a.y); r[2]=f2bf(a.z); r[3]=f2bf(a.w);
    r[4]=f2bf(b.x); r[5]=f2bf(b.y); r[6]=f2bf(b.z); r[7]=f2bf(b.w);
    return r;
}

// ---- pre-kernel 1: K f32 -> bf16 ----
__global__ __launch_bounds__(256)
void convk_kernel(const float* __restrict__ src, short* __restrict__ dst) {
    size_t i = (size_t)blockIdx.x * 256 + threadIdx.x;
    const float4* s = (const float4*)(src + i * 8);
    float4 a = s[0], b = s[1];
    bf16x8 r;
    r[0]=f2bf(a.x); r[1]=f2bf(a.y); r[2]=f2bf(a.z); r[3]=f2bf(a.w);
    r[4]=f2bf(b.x); r[5]=f2bf(b.y); r[6]=f2bf(b.z); r[7]=f2bf(b.w);
    *(bf16x8*)(dst + i * 8) = r;
}

// ---- pre-kernel 2: V [bh][s][d] f32 -> vt [bh][d][s] bf16 ----
__global__ __launch_bounds__(256)
void transv_kernel(const float* __restrict__ v, short* __restrict__ vt) {
    int bh = blockIdx.x >> 4;
    int st = blockIdx.x & 15;
    int wave = threadIdx.x >> 6, lane = threadIdx.x & 63;
    int s0 = st * 64 + wave * 16;
    const float* vp = v + ((size_t)bh * TT + s0) * DD + lane;
    bf16x8 lo, hi;
    #pragma unroll
    for (int e = 0; e < 8; ++e) lo[e] = f2bf(vp[(size_t)e * DD]);
    #pragma unroll
    for (int e = 0; e < 8; ++e) hi[e] = f2bf(vp[(size_t)(e + 8) * DD]);
    short* dp = vt + ((size_t)bh * DD + lane) * TT + s0;
    *(bf16x8*)dp = lo;
    *(bf16x8*)(dp + 8) = hi;
}

__global__ __launch_bounds__(256, 8)
void relattn_kernel(const float* __restrict__ q_g,
                    const short* __restrict__ kb,
                    const short* __restrict__ vt,
                    const float* __restrict__ ek_g,
                    const float* __restrict__ ev_g,
                    float* __restrict__ out_g,
                    float* __restrict__ attn_g) {
    __shared__ __align__(16) char pbuf[QBLK * 2048];     // 16384 B bf16 P, swizzled
    __shared__ float qe_lds[QBLK * NV];                  // 1056 B
    __shared__ float w_lds[QBLK * NV];                   // 1056 B (unnormalized)
    __shared__ float psum_lds[QBLK][4];
    __shared__ float psuf_lds[QBLK][4];
    __shared__ float pmid_lds[QBLK][4];
    __shared__ float inv_lds[QBLK];

    const int t    = threadIdx.x;
    const int bid  = blockIdx.x;
    const int wg   = ((bid & 7) << 10) | (bid >> 3);     // XCD swizzle (8192 blocks)
    const int bh   = wg >> 7;
    const int q0   = (wg & 127) * QBLK;
    const int wave = t >> 6;
    const int lane = t & 63;
    const int lr   = lane & 15;
    const int qr   = lr & 7;                             // valid q-row (dup for lr>=8)
    const int akg  = lane >> 4;

    // Q fragment (B operand of swapped MFMA): Q[q0+qr][...]
    bf16x8 qF0, qF1;
    {
        const float* qp = q_g + ((size_t)bh * TT + q0 + qr) * DD + akg * 8;
        float4 a = *(const float4*)qp,        b = *(const float4*)(qp + 4);
        float4 c = *(const float4*)(qp + 32), d = *(const float4*)(qp + 36);
        qF0 = pack8(a, b); qF1 = pack8(c, d);
    }

    // ---- Phase A: zero w; qe via MFMA (waves 0..2 handle v-tiles) ----
    for (int i = t; i < QBLK * NV; i += 256) w_lds[i] = 0.f;
    if (wave < 3) {
        int v = wave * 16 + lr; if (v > 32) v = 32;
        const float* ep = ek_g + v * DD + akg * 8;
        float4 a = *(const float4*)ep,        b = *(const float4*)(ep + 4);
        float4 c = *(const float4*)(ep + 32), d = *(const float4*)(ep + 36);
        bf16x8 eF0 = pack8(a, b), eF1 = pack8(c, d);
        f32x4 qacc = {0.f, 0.f, 0.f, 0.f};
        qacc = __builtin_amdgcn_mfma_f32_16x16x32_bf16(eF0, qF0, qacc, 0, 0, 0);
        qacc = __builtin_amdgcn_mfma_f32_16x16x32_bf16(eF1, qF1, qacc, 0, 0, 0);
        // lane holds (q-row = lr, v = wave*16 + akg*4 + j)
        if (lr < QBLK) {
            #pragma unroll
            for (int j = 0; j < 4; ++j) {
                int vv = wave * 16 + akg * 4 + j;
                if (vv < NV) qe_lds[lr * NV + vv] = qacc[j] * SCALE;
            }
        }
    }
    __syncthreads();

    // ---- Phase C: swapped QK^T -> exp -> bf16 P + per-lane partial sums ----
    {
        const short* kbase = kb + (size_t)bh * TT * DD;
        const int tq = q0 + lr;
        const int X  = lr << 4;           // lr<8 when used
        float sum = 0.f, suff = 0.f, msum = 0.f;
        #pragma unroll 2
        for (int nt = 0; nt < 16; ++nt) {
            int s0 = wave * 256 + nt * 16;
            const short* kp = kbase + (size_t)(s0 + lr) * DD + akg * 8;
            bf16x8 kF0 = *(const bf16x8*)kp;
            bf16x8 kF1 = *(const bf16x8*)(kp + 32);
            f32x4 acc = {0.f, 0.f, 0.f, 0.f};
            acc = __builtin_amdgcn_mfma_f32_16x16x32_bf16(kF0, qF0, acc, 0, 0, 0);
            acc = __builtin_amdgcn_mfma_f32_16x16x32_bf16(kF1, qF1, acc, 0, 0, 0);
            // lane holds S^T: (q-row = lr, s = s0 + akg*4 + j)
            if (lr < QBLK) {
                const int sb = s0 + akg * 4;
                float e[4];
                #pragma unroll
                for (int j = 0; j < 4; ++j) {
                    int dlt = sb + j - tq;
                    dlt = dlt < -MAXREL ? -MAXREL : (dlt > MAXREL ? MAXREL : dlt);
                    e[j] = __expf(acc[j] * SCALE + qe_lds[lr * NV + dlt + MAXREL]);
                }
                float csum = (e[0] + e[1]) + (e[2] + e[3]);
                sum += csum;
                if (sb >= tq + MAXREL) {
                    suff += csum;
                } else if (sb + 3 >= tq + MAXREL) {
                    #pragma unroll
                    for (int j = 0; j < 4; ++j)
                        if (sb + j >= tq + MAXREL) suff += e[j];
                }
                if (sb + 3 > tq - MAXREL && sb < tq + MAXREL) {
                    #pragma unroll
                    for (int j = 0; j < 4; ++j) {
                        int d = sb + j - tq;
                        if (d > -MAXREL && d < MAXREL) {
                            w_lds[lr * NV + d + MAXREL] = e[j];
                            msum += e[j];
                        }
                    }
                }
                bf16x4 p4;
                p4[0]=f2bf(e[0]); p4[1]=f2bf(e[1]); p4[2]=f2bf(e[2]); p4[3]=f2bf(e[3]);
                *(bf16x4*)(pbuf + lr * 2048 + ((2 * sb) ^ X)) = p4;
            }
        }
        sum  += __shfl_xor(sum, 16);  sum  += __shfl_xor(sum, 32);
        suff += __shfl_xor(suff, 16); suff += __shfl_xor(suff, 32);
        msum += __shfl_xor(msum, 16); msum += __shfl_xor(msum, 32);
        if (lane < QBLK) {
            psum_lds[lane][wave] = sum;
            psuf_lds[lane][wave] = suff;
            pmid_lds[lane][wave] = msum;
        }
    }
    __syncthreads();

    // ---- D1: finalize per-row sums ----
    if (t < QBLK) {
        float s  = (psum_lds[t][0] + psum_lds[t][1]) + (psum_lds[t][2] + psum_lds[t][3]);
        float sf = (psuf_lds[t][0] + psuf_lds[t][1]) + (psuf_lds[t][2] + psuf_lds[t][3]);
        float sm = (pmid_lds[t][0] + pmid_lds[t][1]) + (pmid_lds[t][2] + pmid_lds[t][3]);
        inv_lds[t] = 1.0f / s;
        w_lds[t * NV]      = s - sf - sm;   // prefix weight (v=0)
        w_lds[t * NV + 32] = sf;            // suffix weight (v=32)
    }
    __syncthreads();

    // ---- Phase F: out = inv * (P V + w . emb_v) ----
    {
        const int lc = lane & 15;
        const int pr = lc & 7;                        // P row (dup for lc>=8)
        const int dcol = wave * 16 + lc;
        const short* vbase = vt + ((size_t)bh * DD + dcol) * TT;
        const int X = pr << 4;
        f32x4 acc = {0.f, 0.f, 0.f, 0.f};
        #pragma unroll 8
        for (int kt = 0; kt < 32; ++kt) {
            bf16x8 aF = *(const bf16x8*)(pbuf + pr * 2048 + ((kt * 64 + akg * 16) ^ X));
            bf16x8 bF = *(const bf16x8*)(vbase + kt * 32 + akg * 8);
            acc = __builtin_amdgcn_mfma_f32_16x16x32_bf16(aF, bF, acc, 0, 0, 0);
        }
        // out rows = akg*4 + j; only akg<2 rows are valid (0..7)
        if (akg < 2) {
            const int rb = akg * 4;
            float o0 = acc[0], o1 = acc[1], o2 = acc[2], o3 = acc[3];
            #pragma unroll 4
            for (int v = 0; v < NV; ++v) {
                float ev = ev_g[v * DD + dcol];
                o0 += w_lds[(rb + 0) * NV + v] * ev;
                o1 += w_lds[(rb + 1) * NV + v] * ev;
                o2 += w_lds[(rb + 2) * NV + v] * ev;
                o3 += w_lds[(rb + 3) * NV + v] * ev;
            }
            float* op = out_g + ((size_t)bh * TT + q0 + rb) * DD + dcol;
            op[0 * DD] = o0 * inv_lds[rb + 0];
            op[1 * DD] = o1 * inv_lds[rb + 1];
            op[2 * DD] = o2 * inv_lds[rb + 2];
            op[3 * DD] = o3 * inv_lds[rb + 3];
        }
    }

    // ---- D2: normalized attn write (nontemporal, coalesced) ----
    {
        float* ab = attn_g + ((size_t)bh * TT + q0) * TT;
        #pragma unroll
        for (int j = 0; j < 2; ++j) {
            const int r = wave * 2 + j;
            const float inv = inv_lds[r];
            const int X = r << 4;
            #pragma unroll
            for (int i = 0; i < 4; ++i) {
                bf16x4 p4 = *(const bf16x4*)(pbuf + r * 2048 + ((8 * lane + 512 * i) ^ X));
                f32x4 o;
                o[0] = bf2f(p4[0]) * inv; o[1] = bf2f(p4[1]) * inv;
                o[2] = bf2f(p4[2]) * inv; o[3] = bf2f(p4[3]) * inv;
                __builtin_nontemporal_store(o, (f32x4*)(ab + (size_t)r * TT + lane * 4 + 256 * i));
            }
        }
    }
}

extern "C" void kernel_launch(void* const* d_in, const int* in_sizes, int n_in,
                              void* d_out, int out_size, void* d_ws, size_t ws_size,
                              hipStream_t stream) {
    const float* q  = (const float*)d_in[0];
    const float* k  = (const float*)d_in[1];
    const float* v  = (const float*)d_in[2];
    const float* ek = (const float*)d_in[3];
    const float* ev = (const float*)d_in[4];
    float* out  = (float*)d_out;
    float* attn = out + (size_t)BH * TT * DD;

    short* kbuf = (short*)d_ws;
    short* vtb  = kbuf + (size_t)BH * TT * DD;

    convk_kernel<<<dim3(2048), dim3(256), 0, stream>>>(k, kbuf);
    transv_kernel<<<dim3(1024), dim3(256), 0, stream>>>(v, vtb);
    relattn_kernel<<<dim3(8192), dim3(256), 0, stream>>>(q, kbuf, vtb, ek, ev, out, attn);
}

// Round 7
// 170.779 us; speedup vs baseline: 1.6676x; 1.6676x over previous
//
#include <hip/hip_runtime.h>

#define TT 1024
#define DD 64
#define MAXREL 16
#define NV 33
#define QBLK 16
#define SCALE 0.125f
#define BH 64

typedef short bf16x8 __attribute__((ext_vector_type(8)));
typedef short bf16x4 __attribute__((ext_vector_type(4)));
typedef float f32x4 __attribute__((ext_vector_type(4)));

static __device__ inline short f2bf(float f) {
    union { float f; unsigned u; } x; x.f = f;
    unsigned u = x.u;
    u += 0x7fff + ((u >> 16) & 1);   // RNE
    return (short)(u >> 16);
}
static __device__ inline float bf2f(short s) {
    union { unsigned u; float f; } x;
    x.u = ((unsigned)(unsigned short)s) << 16;
    return x.f;
}
static __device__ inline bf16x8 pack8(float4 a, float4 b) {
    bf16x8 r;
    r[0]=f2bf(a.x); r[1]=f2bf(a.y); r[2]=f2bf(a.z); r[3]=f2bf(a.w);
    r[4]=f2bf(b.x); r[5]=f2bf(b.y); r[6]=f2bf(b.z); r[7]=f2bf(b.w);
    return r;
}

// ---- pre-kernel 1: K f32 -> bf16 ----
__global__ __launch_bounds__(256)
void convk_kernel(const float* __restrict__ src, short* __restrict__ dst) {
    size_t i = (size_t)blockIdx.x * 256 + threadIdx.x;
    const float4* s = (const float4*)(src + i * 8);
    float4 a = s[0], b = s[1];
    bf16x8 r;
    r[0]=f2bf(a.x); r[1]=f2bf(a.y); r[2]=f2bf(a.z); r[3]=f2bf(a.w);
    r[4]=f2bf(b.x); r[5]=f2bf(b.y); r[6]=f2bf(b.z); r[7]=f2bf(b.w);
    *(bf16x8*)(dst + i * 8) = r;
}

// ---- pre-kernel 2: V [bh][s][d] f32 -> vt [bh][d][s] bf16 ----
__global__ __launch_bounds__(256)
void transv_kernel(const float* __restrict__ v, short* __restrict__ vt) {
    int bh = blockIdx.x >> 4;
    int st = blockIdx.x & 15;
    int wave = threadIdx.x >> 6, lane = threadIdx.x & 63;
    int s0 = st * 64 + wave * 16;
    const float* vp = v + ((size_t)bh * TT + s0) * DD + lane;
    bf16x8 lo, hi;
    #pragma unroll
    for (int e = 0; e < 8; ++e) lo[e] = f2bf(vp[(size_t)e * DD]);
    #pragma unroll
    for (int e = 0; e < 8; ++e) hi[e] = f2bf(vp[(size_t)(e + 8) * DD]);
    short* dp = vt + ((size_t)bh * DD + lane) * TT + s0;
    *(bf16x8*)dp = lo;
    *(bf16x8*)(dp + 8) = hi;
}

__global__ __launch_bounds__(256, 4)
void relattn_kernel(const float* __restrict__ q_g,
                    const short* __restrict__ kb,
                    const short* __restrict__ vt,
                    const float* __restrict__ ek_g,
                    const float* __restrict__ ev_g,
                    float* __restrict__ out_g,
                    float* __restrict__ attn_g) {
    __shared__ __align__(16) char pbuf[QBLK * 2048];     // 32768 B bf16 P, swizzled
    __shared__ float qe_lds[QBLK * NV];                  // holds eqe = exp(qe/8)
    __shared__ float w_lds[QBLK * NV];                   // unnormalized w
    __shared__ float psum_lds[QBLK][4];
    __shared__ float psuf_lds[QBLK][4];
    __shared__ float pmid_lds[QBLK][4];
    __shared__ float inv_lds[QBLK];

    const int t    = threadIdx.x;
    const int bid  = blockIdx.x;
    const int wg   = ((bid & 7) << 9) | (bid >> 3);      // XCD swizzle
    const int bh   = wg >> 6;
    const int q0   = (wg & 63) * QBLK;
    const int wave = t >> 6;
    const int lane = t & 63;
    const int lr   = lane & 15;
    const int akg  = lane >> 4;

    // Q fragment (B operand of swapped MFMA): Q[q0+lr][...]
    bf16x8 qF0, qF1;
    {
        const float* qp = q_g + ((size_t)bh * TT + q0 + lr) * DD + akg * 8;
        float4 a = *(const float4*)qp,        b = *(const float4*)(qp + 4);
        float4 c = *(const float4*)(qp + 32), d = *(const float4*)(qp + 36);
        qF0 = pack8(a, b); qF1 = pack8(c, d);
    }

    // ---- Phase A: zero w; eqe = exp(qe/8) via MFMA (waves 0..2) ----
    for (int i = t; i < QBLK * NV; i += 256) w_lds[i] = 0.f;
    if (wave < 3) {
        int v = wave * 16 + lr; if (v > 32) v = 32;
        const float* ep = ek_g + v * DD + akg * 8;
        float4 a = *(const float4*)ep,        b = *(const float4*)(ep + 4);
        float4 c = *(const float4*)(ep + 32), d = *(const float4*)(ep + 36);
        bf16x8 eF0 = pack8(a, b), eF1 = pack8(c, d);
        f32x4 qacc = {0.f, 0.f, 0.f, 0.f};
        qacc = __builtin_amdgcn_mfma_f32_16x16x32_bf16(eF0, qF0, qacc, 0, 0, 0);
        qacc = __builtin_amdgcn_mfma_f32_16x16x32_bf16(eF1, qF1, qacc, 0, 0, 0);
        #pragma unroll
        for (int j = 0; j < 4; ++j) {
            int vv = wave * 16 + akg * 4 + j;
            if (vv < NV) qe_lds[lr * NV + vv] = __expf(qacc[j] * SCALE);
        }
    }
    __syncthreads();

    // ---- Phase C: swapped QK^T -> e = exp(s)*eqe -> bf16 P + partial sums ----
    {
        const short* kp0 = kb + (size_t)bh * TT * DD
                         + (size_t)(wave * 256 + lr) * DD + akg * 8;
        const int tq = q0 + lr;
        const int X  = (lr & 7) << 4;
        const float eqe_lo = qe_lds[lr * NV];
        const float eqe_hi = qe_lds[lr * NV + 32];
        float sum = 0.f, suff = 0.f, msum = 0.f;
        #pragma unroll
        for (int nt = 0; nt < 16; ++nt) {
            bf16x8 kF0 = *(const bf16x8*)(kp0 + nt * 1024);
            bf16x8 kF1 = *(const bf16x8*)(kp0 + nt * 1024 + 32);
            f32x4 acc = {0.f, 0.f, 0.f, 0.f};
            acc = __builtin_amdgcn_mfma_f32_16x16x32_bf16(kF0, qF0, acc, 0, 0, 0);
            acc = __builtin_amdgcn_mfma_f32_16x16x32_bf16(kF1, qF1, acc, 0, 0, 0);
            const int sb = wave * 256 + nt * 16 + akg * 4;
            float ex[4], e[4];
            #pragma unroll
            for (int j = 0; j < 4; ++j) ex[j] = __expf(acc[j] * SCALE);
            if (sb >= tq + MAXREL) {               // fully suffix
                #pragma unroll
                for (int j = 0; j < 4; ++j) e[j] = ex[j] * eqe_hi;
                float csum = (e[0] + e[1]) + (e[2] + e[3]);
                sum += csum; suff += csum;
            } else if (sb + 3 <= tq - MAXREL) {    // fully prefix
                #pragma unroll
                for (int j = 0; j < 4; ++j) e[j] = ex[j] * eqe_lo;
                sum += (e[0] + e[1]) + (e[2] + e[3]);
            } else {                               // diagonal band (rare)
                #pragma unroll
                for (int j = 0; j < 4; ++j) {
                    int dr = sb + j - tq;
                    int dc = dr < -MAXREL ? -MAXREL : (dr > MAXREL ? MAXREL : dr);
                    float ee = ex[j] * qe_lds[lr * NV + dc + MAXREL];
                    e[j] = ee;
                    sum += ee;
                    if (dr >= MAXREL) suff += ee;
                    if (dr > -MAXREL && dr < MAXREL) {
                        w_lds[lr * NV + dr + MAXREL] = ee;
                        msum += ee;
                    }
                }
            }
            bf16x4 p4;
            p4[0]=f2bf(e[0]); p4[1]=f2bf(e[1]); p4[2]=f2bf(e[2]); p4[3]=f2bf(e[3]);
            *(bf16x4*)(pbuf + lr * 2048 + ((2 * sb) ^ X)) = p4;
        }
        sum  += __shfl_xor(sum, 16);  sum  += __shfl_xor(sum, 32);
        suff += __shfl_xor(suff, 16); suff += __shfl_xor(suff, 32);
        msum += __shfl_xor(msum, 16); msum += __shfl_xor(msum, 32);
        if (lane < 16) {
            psum_lds[lr][wave] = sum;
            psuf_lds[lr][wave] = suff;
            pmid_lds[lr][wave] = msum;
        }
    }
    __syncthreads();

    // ---- D1: finalize per-row sums ----
    if (t < QBLK) {
        float s  = (psum_lds[t][0] + psum_lds[t][1]) + (psum_lds[t][2] + psum_lds[t][3]);
        float sf = (psuf_lds[t][0] + psuf_lds[t][1]) + (psuf_lds[t][2] + psuf_lds[t][3]);
        float sm = (pmid_lds[t][0] + pmid_lds[t][1]) + (pmid_lds[t][2] + pmid_lds[t][3]);
        inv_lds[t] = 1.0f / s;
        w_lds[t * NV]      = s - sf - sm;   // prefix weight (v=0)
        w_lds[t * NV + 32] = sf;            // suffix weight (v=32)
    }
    __syncthreads();

    // ---- Phase F: out = inv * (P V + w . emb_v), grouped loads ----
    {
        const int lc = lane & 15;
        const int dcol = wave * 16 + lc;
        const short* vbase = vt + ((size_t)bh * DD + dcol) * TT + akg * 8;
        const char* pb = pbuf + lc * 2048;
        const int X = (lc & 7) << 4;
        f32x4 acc = {0.f, 0.f, 0.f, 0.f};
        #pragma unroll
        for (int g = 0; g < 8; ++g) {
            bf16x8 v0 = *(const bf16x8*)(vbase + (4*g+0) * 32);
            bf16x8 v1 = *(const bf16x8*)(vbase + (4*g+1) * 32);
            bf16x8 v2 = *(const bf16x8*)(vbase + (4*g+2) * 32);
            bf16x8 v3 = *(const bf16x8*)(vbase + (4*g+3) * 32);
            bf16x8 a0 = *(const bf16x8*)(pb + (((4*g+0) * 64 + akg * 16) ^ X));
            bf16x8 a1 = *(const bf16x8*)(pb + (((4*g+1) * 64 + akg * 16) ^ X));
            bf16x8 a2 = *(const bf16x8*)(pb + (((4*g+2) * 64 + akg * 16) ^ X));
            bf16x8 a3 = *(const bf16x8*)(pb + (((4*g+3) * 64 + akg * 16) ^ X));
            acc = __builtin_amdgcn_mfma_f32_16x16x32_bf16(a0, v0, acc, 0, 0, 0);
            acc = __builtin_amdgcn_mfma_f32_16x16x32_bf16(a1, v1, acc, 0, 0, 0);
            acc = __builtin_amdgcn_mfma_f32_16x16x32_bf16(a2, v2, acc, 0, 0, 0);
            acc = __builtin_amdgcn_mfma_f32_16x16x32_bf16(a3, v3, acc, 0, 0, 0);
        }
        const int rb = akg * 4;
        float o0 = acc[0], o1 = acc[1], o2 = acc[2], o3 = acc[3];
        #pragma unroll 8
        for (int v = 0; v < NV; ++v) {
            float ev = ev_g[v * DD + dcol];
            o0 += w_lds[(rb + 0) * NV + v] * ev;
            o1 += w_lds[(rb + 1) * NV + v] * ev;
            o2 += w_lds[(rb + 2) * NV + v] * ev;
            o3 += w_lds[(rb + 3) * NV + v] * ev;
        }
        float* op = out_g + ((size_t)bh * TT + q0 + rb) * DD + dcol;
        op[0 * DD] = o0 * inv_lds[rb + 0];
        op[1 * DD] = o1 * inv_lds[rb + 1];
        op[2 * DD] = o2 * inv_lds[rb + 2];
        op[3 * DD] = o3 * inv_lds[rb + 3];
    }

    // ---- D2: normalized attn write (nontemporal, coalesced) ----
    {
        float* ab = attn_g + ((size_t)bh * TT + q0) * TT;
        #pragma unroll
        for (int j = 0; j < 4; ++j) {
            const int r = wave * 4 + j;
            const float inv = inv_lds[r];
            const int X = (r & 7) << 4;
            #pragma unroll
            for (int i = 0; i < 4; ++i) {
                bf16x4 p4 = *(const bf16x4*)(pbuf + r * 2048 + ((8 * lane + 512 * i) ^ X));
                f32x4 o;
                o[0] = bf2f(p4[0]) * inv; o[1] = bf2f(p4[1]) * inv;
                o[2] = bf2f(p4[2]) * inv; o[3] = bf2f(p4[3]) * inv;
                __builtin_nontemporal_store(o, (f32x4*)(ab + (size_t)r * TT + lane * 4 + 256 * i));
            }
        }
    }
}

extern "C" void kernel_launch(void* const* d_in, const int* in_sizes, int n_in,
                              void* d_out, int out_size, void* d_ws, size_t ws_size,
                              hipStream_t stream) {
    const float* q  = (const float*)d_in[0];
    const float* k  = (const float*)d_in[1];
    const float* v  = (const float*)d_in[2];
    const float* ek = (const float*)d_in[3];
    const float* ev = (const float*)d_in[4];
    float* out  = (float*)d_out;
    float* attn = out + (size_t)BH * TT * DD;

    short* kbuf = (short*)d_ws;
    short* vtb  = kbuf + (size_t)BH * TT * DD;

    convk_kernel<<<dim3(2048), dim3(256), 0, stream>>>(k, kbuf);
    transv_kernel<<<dim3(1024), dim3(256), 0, stream>>>(v, vtb);
    relattn_kernel<<<dim3(4096), dim3(256), 0, stream>>>(q, kbuf, vtb, ek, ev, out, attn);
}

// Round 8
// 160.441 us; speedup vs baseline: 1.7751x; 1.0644x over previous
//
#include <hip/hip_runtime.h>
#include <hip/hip_bf16.h>

#define TT 1024
#define DD 64
#define MAXREL 16
#define NV 33
#define QBLK 16
#define SCALE 0.125f
#define BH 64

typedef short bf16x8 __attribute__((ext_vector_type(8)));
typedef short bf16x4 __attribute__((ext_vector_type(4)));
typedef float f32x4 __attribute__((ext_vector_type(4)));

static __device__ inline short f2bf(float f) {
    __hip_bfloat16 h = __float2bfloat16(f);   // RNE; compiler emits v_cvt_pk_bf16_f32
    return *(short*)&h;
}
static __device__ inline float bf2f(short s) {
    union { unsigned u; float f; } x;
    x.u = ((unsigned)(unsigned short)s) << 16;
    return x.f;
}
static __device__ inline bf16x8 pack8(float4 a, float4 b) {
    bf16x8 r;
    r[0]=f2bf(a.x); r[1]=f2bf(a.y); r[2]=f2bf(a.z); r[3]=f2bf(a.w);
    r[4]=f2bf(b.x); r[5]=f2bf(b.y); r[6]=f2bf(b.z); r[7]=f2bf(b.w);
    return r;
}

// ---- pre-kernel 1: K f32 -> bf16 ----
__global__ __launch_bounds__(256)
void convk_kernel(const float* __restrict__ src, short* __restrict__ dst) {
    size_t i = (size_t)blockIdx.x * 256 + threadIdx.x;
    const float4* s = (const float4*)(src + i * 8);
    *(bf16x8*)(dst + i * 8) = pack8(s[0], s[1]);
}

// ---- pre-kernel 2: V [bh][s][d] f32 -> vt [bh][d][s] bf16 ----
__global__ __launch_bounds__(256)
void transv_kernel(const float* __restrict__ v, short* __restrict__ vt) {
    int bh = blockIdx.x >> 4;
    int st = blockIdx.x & 15;
    int wave = threadIdx.x >> 6, lane = threadIdx.x & 63;
    int s0 = st * 64 + wave * 16;
    const float* vp = v + ((size_t)bh * TT + s0) * DD + lane;
    bf16x8 lo, hi;
    #pragma unroll
    for (int e = 0; e < 8; ++e) lo[e] = f2bf(vp[(size_t)e * DD]);
    #pragma unroll
    for (int e = 0; e < 8; ++e) hi[e] = f2bf(vp[(size_t)(e + 8) * DD]);
    short* dp = vt + ((size_t)bh * DD + lane) * TT + s0;
    *(bf16x8*)dp = lo;
    *(bf16x8*)(dp + 8) = hi;
}

__global__ __launch_bounds__(256, 4)
void relattn_kernel(const float* __restrict__ q_g,
                    const short* __restrict__ kb,
                    const short* __restrict__ vt,
                    const float* __restrict__ ek_g,
                    const float* __restrict__ ev_g,
                    float* __restrict__ out_g,
                    float* __restrict__ attn_g) {
    __shared__ __align__(16) char pbuf[QBLK * 2048];     // 32768 B bf16 P, swizzled
    __shared__ float qe_lds[QBLK * NV];                  // holds eqe = exp(qe/8)
    __shared__ float w_lds[QBLK * NV];                   // unnormalized w
    __shared__ float psum_lds[QBLK][4];
    __shared__ float psuf_lds[QBLK][4];
    __shared__ float pmid_lds[QBLK][4];
    __shared__ float inv_lds[QBLK];

    const int t    = threadIdx.x;
    const int bid  = blockIdx.x;
    const int wg   = ((bid & 7) << 9) | (bid >> 3);      // XCD swizzle
    const int bh   = wg >> 6;
    const int q0   = (wg & 63) * QBLK;
    const int wave = t >> 6;
    const int lane = t & 63;
    const int lr   = lane & 15;
    const int akg  = lane >> 4;

    // Q fragment (B operand of swapped MFMA): Q[q0+lr][...]
    bf16x8 qF0, qF1;
    {
        const float* qp = q_g + ((size_t)bh * TT + q0 + lr) * DD + akg * 8;
        float4 a = *(const float4*)qp,        b = *(const float4*)(qp + 4);
        float4 c = *(const float4*)(qp + 32), d = *(const float4*)(qp + 36);
        qF0 = pack8(a, b); qF1 = pack8(c, d);
    }

    // ---- Phase A: zero w; eqe = exp(qe/8) via MFMA (waves 0..2) ----
    for (int i = t; i < QBLK * NV; i += 256) w_lds[i] = 0.f;
    if (wave < 3) {
        int v = wave * 16 + lr; if (v > 32) v = 32;
        const float* ep = ek_g + v * DD + akg * 8;
        float4 a = *(const float4*)ep,        b = *(const float4*)(ep + 4);
        float4 c = *(const float4*)(ep + 32), d = *(const float4*)(ep + 36);
        bf16x8 eF0 = pack8(a, b), eF1 = pack8(c, d);
        f32x4 qacc = {0.f, 0.f, 0.f, 0.f};
        qacc = __builtin_amdgcn_mfma_f32_16x16x32_bf16(eF0, qF0, qacc, 0, 0, 0);
        qacc = __builtin_amdgcn_mfma_f32_16x16x32_bf16(eF1, qF1, qacc, 0, 0, 0);
        #pragma unroll
        for (int j = 0; j < 4; ++j) {
            int vv = wave * 16 + akg * 4 + j;
            if (vv < NV) qe_lds[lr * NV + vv] = __expf(qacc[j] * SCALE);
        }
    }
    __syncthreads();

    // ---- Phase C: swapped QK^T -> e = exp(s)*eqe -> bf16 P + partial sums ----
    {
        const short* kp0 = kb + (size_t)bh * TT * DD
                         + (size_t)(wave * 256 + lr) * DD + akg * 8;
        const int tq = q0 + lr;
        const int X  = (lr & 7) << 4;
        const float eqe_lo = qe_lds[lr * NV];
        const float eqe_hi = qe_lds[lr * NV + 32];
        float sum = 0.f, suff = 0.f, msum = 0.f;

        auto CCOMP = [&](bf16x8 kf0, bf16x8 kf1, int nt) {
            f32x4 acc = {0.f, 0.f, 0.f, 0.f};
            acc = __builtin_amdgcn_mfma_f32_16x16x32_bf16(kf0, qF0, acc, 0, 0, 0);
            acc = __builtin_amdgcn_mfma_f32_16x16x32_bf16(kf1, qF1, acc, 0, 0, 0);
            const int sb = wave * 256 + nt * 16 + akg * 4;
            float ex0 = __expf(acc[0] * SCALE), ex1 = __expf(acc[1] * SCALE);
            float ex2 = __expf(acc[2] * SCALE), ex3 = __expf(acc[3] * SCALE);
            float e0, e1, e2, e3;
            if (sb >= tq + MAXREL) {               // fully suffix
                e0 = ex0 * eqe_hi; e1 = ex1 * eqe_hi;
                e2 = ex2 * eqe_hi; e3 = ex3 * eqe_hi;
                float csum = (e0 + e1) + (e2 + e3);
                sum += csum; suff += csum;
            } else if (sb + 3 <= tq - MAXREL) {    // fully prefix
                e0 = ex0 * eqe_lo; e1 = ex1 * eqe_lo;
                e2 = ex2 * eqe_lo; e3 = ex3 * eqe_lo;
                sum += (e0 + e1) + (e2 + e3);
            } else {                               // diagonal band (rare)
                float ee[4]; float exs[4] = {ex0, ex1, ex2, ex3};
                #pragma unroll
                for (int j = 0; j < 4; ++j) {
                    int dr = sb + j - tq;
                    int dc = dr < -MAXREL ? -MAXREL : (dr > MAXREL ? MAXREL : dr);
                    float v = exs[j] * qe_lds[lr * NV + dc + MAXREL];
                    ee[j] = v;
                    sum += v;
                    if (dr >= MAXREL) suff += v;
                    if (dr > -MAXREL && dr < MAXREL) {
                        w_lds[lr * NV + dr + MAXREL] = v;
                        msum += v;
                    }
                }
                e0 = ee[0]; e1 = ee[1]; e2 = ee[2]; e3 = ee[3];
            }
            bf16x4 p4;
            p4[0] = f2bf(e0); p4[1] = f2bf(e1);
            p4[2] = f2bf(e2); p4[3] = f2bf(e3);
            *(bf16x4*)(pbuf + lr * 2048 + ((2 * sb) ^ X)) = p4;
        };

        bf16x8 kA0, kA1, kB0, kB1, kC0, kC1, kD0, kD1;
        #define KLD(R0, R1, NT) \
            R0 = *(const bf16x8*)(kp0 + (NT) * 1024); \
            R1 = *(const bf16x8*)(kp0 + (NT) * 1024 + 32)
        KLD(kA0, kA1, 0);  KLD(kB0, kB1, 1);
        KLD(kC0, kC1, 2);  CCOMP(kA0, kA1, 0);
        KLD(kD0, kD1, 3);  CCOMP(kB0, kB1, 1);
        KLD(kA0, kA1, 4);  CCOMP(kC0, kC1, 2);
        KLD(kB0, kB1, 5);  CCOMP(kD0, kD1, 3);
        KLD(kC0, kC1, 6);  CCOMP(kA0, kA1, 4);
        KLD(kD0, kD1, 7);  CCOMP(kB0, kB1, 5);
        KLD(kA0, kA1, 8);  CCOMP(kC0, kC1, 6);
        KLD(kB0, kB1, 9);  CCOMP(kD0, kD1, 7);
        KLD(kC0, kC1, 10); CCOMP(kA0, kA1, 8);
        KLD(kD0, kD1, 11); CCOMP(kB0, kB1, 9);
        KLD(kA0, kA1, 12); CCOMP(kC0, kC1, 10);
        KLD(kB0, kB1, 13); CCOMP(kD0, kD1, 11);
        KLD(kC0, kC1, 14); CCOMP(kA0, kA1, 12);
        KLD(kD0, kD1, 15); CCOMP(kB0, kB1, 13);
        CCOMP(kC0, kC1, 14);
        CCOMP(kD0, kD1, 15);
        #undef KLD

        sum  += __shfl_xor(sum, 16);  sum  += __shfl_xor(sum, 32);
        suff += __shfl_xor(suff, 16); suff += __shfl_xor(suff, 32);
        msum += __shfl_xor(msum, 16); msum += __shfl_xor(msum, 32);
        if (lane < 16) {
            psum_lds[lr][wave] = sum;
            psuf_lds[lr][wave] = suff;
            pmid_lds[lr][wave] = msum;
        }
    }
    __syncthreads();

    // ---- D1: finalize per-row sums ----
    if (t < QBLK) {
        float s  = (psum_lds[t][0] + psum_lds[t][1]) + (psum_lds[t][2] + psum_lds[t][3]);
        float sf = (psuf_lds[t][0] + psuf_lds[t][1]) + (psuf_lds[t][2] + psuf_lds[t][3]);
        float sm = (pmid_lds[t][0] + pmid_lds[t][1]) + (pmid_lds[t][2] + pmid_lds[t][3]);
        inv_lds[t] = 1.0f / s;
        w_lds[t * NV]      = s - sf - sm;   // prefix weight (v=0)
        w_lds[t * NV + 32] = sf;            // suffix weight (v=32)
    }
    __syncthreads();

    // ---- Phase F: out = inv * (P V + w . emb_v), rotating V prefetch ----
    {
        const int lc = lane & 15;
        const int dcol = wave * 16 + lc;
        const short* vbase = vt + ((size_t)bh * DD + dcol) * TT + akg * 8;
        const char* pb = pbuf + lc * 2048;
        const int X = (lc & 7) << 4;
        f32x4 acc = {0.f, 0.f, 0.f, 0.f};

        auto FCOMP = [&](bf16x8 v0, bf16x8 v1, bf16x8 v2, bf16x8 v3, int g) {
            bf16x8 a0 = *(const bf16x8*)(pb + (((4*g+0) * 64 + akg * 16) ^ X));
            bf16x8 a1 = *(const bf16x8*)(pb + (((4*g+1) * 64 + akg * 16) ^ X));
            bf16x8 a2 = *(const bf16x8*)(pb + (((4*g+2) * 64 + akg * 16) ^ X));
            bf16x8 a3 = *(const bf16x8*)(pb + (((4*g+3) * 64 + akg * 16) ^ X));
            acc = __builtin_amdgcn_mfma_f32_16x16x32_bf16(a0, v0, acc, 0, 0, 0);
            acc = __builtin_amdgcn_mfma_f32_16x16x32_bf16(a1, v1, acc, 0, 0, 0);
            acc = __builtin_amdgcn_mfma_f32_16x16x32_bf16(a2, v2, acc, 0, 0, 0);
            acc = __builtin_amdgcn_mfma_f32_16x16x32_bf16(a3, v3, acc, 0, 0, 0);
        };

        bf16x8 vA0, vA1, vA2, vA3, vB0, vB1, vB2, vB3;
        #define VLD(R0, R1, R2, R3, G) \
            R0 = *(const bf16x8*)(vbase + (4*(G)+0) * 32); \
            R1 = *(const bf16x8*)(vbase + (4*(G)+1) * 32); \
            R2 = *(const bf16x8*)(vbase + (4*(G)+2) * 32); \
            R3 = *(const bf16x8*)(vbase + (4*(G)+3) * 32)
        VLD(vA0, vA1, vA2, vA3, 0);
        VLD(vB0, vB1, vB2, vB3, 1); FCOMP(vA0, vA1, vA2, vA3, 0);
        VLD(vA0, vA1, vA2, vA3, 2); FCOMP(vB0, vB1, vB2, vB3, 1);
        VLD(vB0, vB1, vB2, vB3, 3); FCOMP(vA0, vA1, vA2, vA3, 2);
        VLD(vA0, vA1, vA2, vA3, 4); FCOMP(vB0, vB1, vB2, vB3, 3);
        VLD(vB0, vB1, vB2, vB3, 5); FCOMP(vA0, vA1, vA2, vA3, 4);
        VLD(vA0, vA1, vA2, vA3, 6); FCOMP(vB0, vB1, vB2, vB3, 5);
        VLD(vB0, vB1, vB2, vB3, 7); FCOMP(vA0, vA1, vA2, vA3, 6);
        FCOMP(vB0, vB1, vB2, vB3, 7);
        #undef VLD

        const int rb = akg * 4;
        float o0 = acc[0], o1 = acc[1], o2 = acc[2], o3 = acc[3];
        #pragma unroll 8
        for (int v = 0; v < NV; ++v) {
            float ev = ev_g[v * DD + dcol];
            o0 += w_lds[(rb + 0) * NV + v] * ev;
            o1 += w_lds[(rb + 1) * NV + v] * ev;
            o2 += w_lds[(rb + 2) * NV + v] * ev;
            o3 += w_lds[(rb + 3) * NV + v] * ev;
        }
        float* op = out_g + ((size_t)bh * TT + q0 + rb) * DD + dcol;
        op[0 * DD] = o0 * inv_lds[rb + 0];
        op[1 * DD] = o1 * inv_lds[rb + 1];
        op[2 * DD] = o2 * inv_lds[rb + 2];
        op[3 * DD] = o3 * inv_lds[rb + 3];
    }

    // ---- D2: normalized attn write (nontemporal, coalesced) ----
    {
        float* ab = attn_g + ((size_t)bh * TT + q0) * TT;
        #pragma unroll
        for (int j = 0; j < 4; ++j) {
            const int r = wave * 4 + j;
            const float inv = inv_lds[r];
            const int X = (r & 7) << 4;
            #pragma unroll
            for (int i = 0; i < 4; ++i) {
                bf16x4 p4 = *(const bf16x4*)(pbuf + r * 2048 + ((8 * lane + 512 * i) ^ X));
                f32x4 o;
                o[0] = bf2f(p4[0]) * inv; o[1] = bf2f(p4[1]) * inv;
                o[2] = bf2f(p4[2]) * inv; o[3] = bf2f(p4[3]) * inv;
                __builtin_nontemporal_store(o, (f32x4*)(ab + (size_t)r * TT + lane * 4 + 256 * i));
            }
        }
    }
}

extern "C" void kernel_launch(void* const* d_in, const int* in_sizes, int n_in,
                              void* d_out, int out_size, void* d_ws, size_t ws_size,
                              hipStream_t stream) {
    const float* q  = (const float*)d_in[0];
    const float* k  = (const float*)d_in[1];
    const float* v  = (const float*)d_in[2];
    const float* ek = (const float*)d_in[3];
    const float* ev = (const float*)d_in[4];
    float* out  = (float*)d_out;
    float* attn = out + (size_t)BH * TT * DD;

    short* kbuf = (short*)d_ws;
    short* vtb  = kbuf + (size_t)BH * TT * DD;

    convk_kernel<<<dim3(2048), dim3(256), 0, stream>>>(k, kbuf);
    transv_kernel<<<dim3(1024), dim3(256), 0, stream>>>(v, vtb);
    relattn_kernel<<<dim3(4096), dim3(256), 0, stream>>>(q, kbuf, vtb, ek, ev, out, attn);
}